// Round 13
// baseline (31.471 us; speedup 1.0000x reference)
//
#include <hip/hip_runtime.h>

#define B_ 256
#define M_ 512
#define N_ 256
#define K_ 16
#define TR 64                 // rows per LDS tile
#define NT 8                  // tiles per block (512 rows = full batch)

typedef __attribute__((ext_vector_type(8))) short short8;
typedef __attribute__((ext_vector_type(4))) float f32x4;

__device__ __forceinline__ unsigned short f2bf(float f) {
    unsigned u = __builtin_bit_cast(unsigned, f);
    u += 0x7FFFu + ((u >> 16) & 1u);       // round-to-nearest-even
    return (unsigned short)(u >> 16);
}
__device__ __forceinline__ float bf2f(unsigned short h) {
    unsigned u = ((unsigned)h) << 16;
    return __builtin_bit_cast(float, u);
}

// ---------------- Fused FM (single kernel, block = full batch) ----------------
// grid = 256 (1 block/CU), 512 threads (8 waves). Block streams its batch's
// 512x256 fp32 x sequentially in 8 tiles of 64 rows:
//   stage: 8 wave-contiguous float4 rounds (8KB/round/block) -> bf16 ->
//          swizzled ds_write ([64][256] bf16, quad ^= row&7)   [R12 proven]
//   mfma : wave (wr=wv&3, wn=wv>>2): rows [wr*16,+16), n-half wn ->
//          4 x mfma_f32_16x16x32_bf16; vB persistent in VGPRs
//   linear: 8 threads/row dot bf16 row quarter-chunks -> lin[] in LDS
// Epilogue (block-local, no grid barrier): n-half partials summed via LDS
// exchange; sv via shuffles+LDS; p computed from register xv; single out write.
__global__ __launch_bounds__(512) void fm_fused(
    const float* __restrict__ x, const float* __restrict__ w,
    const float* __restrict__ bias, const float* __restrict__ v,
    float* __restrict__ out)
{
    __shared__ __align__(16) unsigned char xL[2][TR * 512];  // 2 x 32 KiB bf16
    __shared__ __align__(16) unsigned short wLb[N_];         // w bf16
    __shared__ __align__(16) float lin[M_];                  // linear terms
    __shared__ __align__(16) float red[64];
    __shared__ __align__(16) float svL[16];

    const int t   = threadIdx.x;
    const int l   = t & 63;
    const int wv  = t >> 6;         // 0..7
    const int wr  = wv & 3;         // row-quarter within tile
    const int wn  = wv >> 2;        // n-half
    const int b   = blockIdx.x;
    const float bias0 = bias[0];

    // stage w as bf16
    if (t < 64) {
        float4 wq = *(const float4*)(w + t * 4);
        wLb[t * 4 + 0] = f2bf(wq.x); wLb[t * 4 + 1] = f2bf(wq.y);
        wLb[t * 4 + 2] = f2bf(wq.z); wLb[t * 4 + 3] = f2bf(wq.w);
    }

    // B-fragments for this wave's n-half: chunks wn*4 .. wn*4+3 (32 n each).
    // 16x16x32 bf16 B layout: col = l&15, k = (l>>4)*8 + j.
    short8 vB[4];
    #pragma unroll
    for (int c = 0; c < 4; ++c) {
        #pragma unroll
        for (int j = 0; j < 8; ++j) {
            float f = v[(size_t)((wn * 4 + c) * 32 + (l >> 4) * 8 + j) * K_ + (l & 15)];
            vB[c][j] = (short)f2bf(f);
        }
    }

    const float* gx = x + (size_t)b * M_ * N_;

    // staging: round j covers rows [j*8, j*8+8): thread -> row j*8+wv,
    // floats [l*4, l*4+4). 8 KB contiguous per round, fully sequential.
    const int swq = l >> 1;          // 16B-quad index within bf16 row
    const int shf = (l & 1) * 8;     // byte within quad

    float4 st[8];
    // prologue: tile 0 -> regs -> bf16 -> buf 0
    #pragma unroll
    for (int j = 0; j < 8; ++j)
        st[j] = *(const float4*)(gx + j * 2048 + t * 4);
    #pragma unroll
    for (int j = 0; j < 8; ++j) {
        const int row = j * 8 + wv;
        unsigned lo = (unsigned)f2bf(st[j].x) | ((unsigned)f2bf(st[j].y) << 16);
        unsigned hi = (unsigned)f2bf(st[j].z) | ((unsigned)f2bf(st[j].w) << 16);
        unsigned* d = (unsigned*)(xL[0] + row * 512 + ((swq ^ (row & 7)) << 4) + shf);
        d[0] = lo; d[1] = hi;
    }
    __syncthreads();

    f32x4 acc[NT];
    #pragma unroll
    for (int T = 0; T < NT; ++T) acc[T] = f32x4{0.f, 0.f, 0.f, 0.f};

    #pragma unroll
    for (int T = 0; T < NT; ++T) {
        const int cur = T & 1;
        // issue next tile's global loads early (hidden under MFMA + linear)
        if (T + 1 < NT) {
            #pragma unroll
            for (int j = 0; j < 8; ++j)
                st[j] = *(const float4*)(gx + (size_t)(T + 1) * TR * N_ + j * 2048 + t * 4);
        }

        // MFMA: rows [wr*16,+16), chunks wn*4..+3.
        // A layout: row = l&15, k = (l>>4)*8 + j.
        const int arow = wr * 16 + (l & 15);
        const unsigned char* abase = xL[cur] + arow * 512;
        #pragma unroll
        for (int c = 0; c < 4; ++c) {
            const int cq = (wn * 4 + c) * 4 + (l >> 4);
            short8 a = *(const short8*)(abase + ((cq ^ (arow & 7)) << 4));
            acc[T] = __builtin_amdgcn_mfma_f32_16x16x32_bf16(a, vB[c], acc[T], 0, 0, 0);
        }

        // linear term: 8 threads/row (row = t>>3, qt = t&7), 32-col chunks
        {
            const int row = t >> 3;
            const int qt  = t & 7;
            const unsigned char* rbase = xL[cur] + row * 512;
            float ls = 0.f;
            #pragma unroll
            for (int i = 0; i < 4; ++i) {
                const int qi = qt * 4 + i;
                short8 xs = *(const short8*)(rbase + ((qi ^ (row & 7)) << 4));
                short8 ws = *(const short8*)((const unsigned char*)wLb + qi * 16);
                #pragma unroll
                for (int e = 0; e < 8; ++e)
                    ls += bf2f((unsigned short)xs[e]) * bf2f((unsigned short)ws[e]);
            }
            ls += __shfl_xor(ls, 1);
            ls += __shfl_xor(ls, 2);
            ls += __shfl_xor(ls, 4);
            if (qt == 0) lin[T * TR + row] = ls;
        }

        // convert + write next tile into the other buffer
        if (T + 1 < NT) {
            #pragma unroll
            for (int j = 0; j < 8; ++j) {
                const int row = j * 8 + wv;
                unsigned lo = (unsigned)f2bf(st[j].x) | ((unsigned)f2bf(st[j].y) << 16);
                unsigned hi = (unsigned)f2bf(st[j].z) | ((unsigned)f2bf(st[j].w) << 16);
                unsigned* d = (unsigned*)(xL[cur ^ 1] + row * 512 + ((swq ^ (row & 7)) << 4) + shf);
                d[0] = lo; d[1] = hi;
            }
        }
        __syncthreads();
    }

    // ---- combine n-half partials: waves wn==1 publish, wn==0 add ----
    // (xL[0] free: last tile used buf 1, all reads drained at loop-end barrier)
    float* exch = (float*)xL[0];            // 4 waves x 64 lanes x 32 floats = 32 KiB
    const int pos = (wr * 64 + l) * 32;
    if (wn == 1) {
        #pragma unroll
        for (int T = 0; T < NT; ++T)
            *(f32x4*)(exch + pos + T * 4) = acc[T];
    }
    __syncthreads();
    if (wn == 0) {
        #pragma unroll
        for (int T = 0; T < NT; ++T) {
            f32x4 o = *(const f32x4*)(exch + pos + T * 4);
            acc[T][0] += o[0]; acc[T][1] += o[1];
            acc[T][2] += o[2]; acc[T][3] += o[3];
        }
    }

    // ---- sv: per-lane row-sum, reduce lanes 16/32, cross-wave via LDS ----
    float s = 0.f;
    if (wn == 0) {
        #pragma unroll
        for (int T = 0; T < NT; ++T)
            s += acc[T][0] + acc[T][1] + acc[T][2] + acc[T][3];
    }
    s += __shfl_xor(s, 16);
    s += __shfl_xor(s, 32);
    if (wn == 0 && l < 16) red[wr * 16 + l] = s;
    __syncthreads();
    if (t < 16) svL[t] = red[t] + red[16 + t] + red[32 + t] + red[48 + t];
    __syncthreads();

    // ---- p from register xv; single out write ----
    // C/D layout: k = l&15, row = T*64 + wr*16 + (l>>4)*4 + r.
    if (wn == 0) {
        const float svk = svL[l & 15];
        #pragma unroll
        for (int T = 0; T < NT; ++T) {
            #pragma unroll
            for (int r = 0; r < 4; ++r) {
                const float a = acc[T][r];
                float q = a * (svk - a);
                q += __shfl_xor(q, 1);
                q += __shfl_xor(q, 2);
                q += __shfl_xor(q, 4);
                q += __shfl_xor(q, 8);
                if ((l & 15) == 0) {
                    const int row = T * TR + wr * 16 + (l >> 4) * 4 + r;
                    out[(size_t)b * M_ + row] = lin[row] + bias0 + 0.5f * q;
                }
            }
        }
    }
}

extern "C" void kernel_launch(void* const* d_in, const int* in_sizes, int n_in,
                              void* d_out, int out_size, void* d_ws, size_t ws_size,
                              hipStream_t stream) {
    const float* x    = (const float*)d_in[0];
    const float* w    = (const float*)d_in[1];
    const float* bias = (const float*)d_in[2];
    const float* v    = (const float*)d_in[3];
    float* out = (float*)d_out;

    fm_fused<<<dim3(B_), dim3(512), 0, stream>>>(x, w, bias, v, out);
}

// Round 14
// 29.719 us; speedup vs baseline: 1.0590x; 1.0590x over previous
//
#include <hip/hip_runtime.h>

#define B_ 256
#define M_ 512
#define N_ 256
#define K_ 16
#define TR 64                 // rows per LDS tile
#define NT 4                  // tiles per block (256 rows)

typedef __attribute__((ext_vector_type(8))) short short8;
typedef __attribute__((ext_vector_type(4))) float f32x4;

__device__ __forceinline__ unsigned short f2bf(float f) {
    unsigned u = __builtin_bit_cast(unsigned, f);
    u += 0x7FFFu + ((u >> 16) & 1u);       // round-to-nearest-even
    return (unsigned short)(u >> 16);
}
__device__ __forceinline__ float bf2f(unsigned short h) {
    unsigned u = ((unsigned)h) << 16;
    return __builtin_bit_cast(float, u);
}

// ---------------- Pass 1 (R12 champion, xv stored bf16) ----------------
// grid = B_*2 = 512 blocks (2/CU), 256 threads (4 waves).
// Block owns 256 rows = 4 tiles x 64 rows x 256 cols. Per tile:
//   stage: 16 wave-contiguous float4 rounds (4KB/instr/block, SEQUENTIAL)
//          -> cvt bf16 -> swizzled ds_write ([64][256] bf16, quad ^= row&7)
//   mfma : wave wv owns rows [wv*16,+16): 8 x mfma_f32_16x16x32_bf16;
//          B-frags (v, bf16) persistent in 32 VGPRs
//   linear: 4 threads/row dot bf16 row with bf16 w from LDS
// xv -> global as bf16 (4.2 MB); sv partial fp32 via shuffles.
__global__ __launch_bounds__(256) void fm_pass1(
    const float* __restrict__ x, const float* __restrict__ w,
    const float* __restrict__ bias, const float* __restrict__ v,
    unsigned short* __restrict__ xvb, float* __restrict__ svpart,
    float* __restrict__ out)
{
    __shared__ __align__(16) unsigned char xL[2][TR * 512];  // 2 x 32 KiB bf16
    __shared__ __align__(16) unsigned short wLb[N_];         // w bf16
    __shared__ __align__(16) float red[64];

    const int t   = threadIdx.x;
    const int l   = t & 63;
    const int wv  = t >> 6;
    const int blk = blockIdx.x;
    const int b   = blk >> 1;
    const int m0  = (blk & 1) * (NT * TR);
    const float bias0 = bias[0];

    // stage w as bf16
    if (t < 64) {
        float4 wq = *(const float4*)(w + t * 4);
        wLb[t * 4 + 0] = f2bf(wq.x); wLb[t * 4 + 1] = f2bf(wq.y);
        wLb[t * 4 + 2] = f2bf(wq.z); wLb[t * 4 + 3] = f2bf(wq.w);
    }

    // B-fragments: v -> bf16, 8 n-chunks, persistent in registers.
    // 16x16x32 bf16 layout: B[k][col]: col = l&15, k = (l>>4)*8 + j.
    short8 vB[8];
    #pragma unroll
    for (int c = 0; c < 8; ++c) {
        #pragma unroll
        for (int j = 0; j < 8; ++j) {
            float f = v[(size_t)(c * 32 + (l >> 4) * 8 + j) * K_ + (l & 15)];
            vB[c][j] = (short)f2bf(f);
        }
    }

    const float* gx = x + (size_t)(b * M_ + m0) * N_;

    // staging geometry: load j covers rows [j*4, j*4+4), wave wv -> row j*4+wv,
    // lane l -> floats [l*4, l*4+4) of that row. 1 KB contiguous per wave-instr.
    const int swq = l >> 1;          // 16B-quad index within row (bf16)
    const int shf = (l & 1) * 8;     // byte within quad

    float4 st[16];
    // prologue: tile 0 -> regs -> bf16 -> buf 0
    #pragma unroll
    for (int j = 0; j < 16; ++j)
        st[j] = *(const float4*)(gx + j * 1024 + t * 4);
    #pragma unroll
    for (int j = 0; j < 16; ++j) {
        const int row = j * 4 + wv;
        unsigned lo = (unsigned)f2bf(st[j].x) | ((unsigned)f2bf(st[j].y) << 16);
        unsigned hi = (unsigned)f2bf(st[j].z) | ((unsigned)f2bf(st[j].w) << 16);
        unsigned* d = (unsigned*)(xL[0] + row * 512 + ((swq ^ (row & 7)) << 4) + shf);
        d[0] = lo; d[1] = hi;
    }
    __syncthreads();

    f32x4 acc[NT];
    #pragma unroll
    for (int T = 0; T < NT; ++T) acc[T] = f32x4{0.f, 0.f, 0.f, 0.f};

    #pragma unroll
    for (int T = 0; T < NT; ++T) {
        const int cur = T & 1;
        // issue next tile's global loads (consumed after MFMA -> latency hidden)
        if (T + 1 < NT) {
            #pragma unroll
            for (int j = 0; j < 16; ++j)
                st[j] = *(const float4*)(gx + (size_t)(T + 1) * TR * N_ + j * 1024 + t * 4);
        }

        // MFMA: wave wv, rows [wv*16, +16). A[row][k]: row = l&15, k = (l>>4)*8+j.
        const int arow = wv * 16 + (l & 15);
        const unsigned char* abase = xL[cur] + arow * 512;
        #pragma unroll
        for (int c = 0; c < 8; ++c) {
            short8 a = *(const short8*)(abase + (((c * 4 + (l >> 4)) ^ (arow & 7)) << 4));
            acc[T] = __builtin_amdgcn_mfma_f32_16x16x32_bf16(a, vB[c], acc[T], 0, 0, 0);
        }

        // linear term for this tile: 4 threads per row, 64-col quarters
        {
            const int row = t >> 2;
            const int qt  = t & 3;
            const unsigned char* rbase = xL[cur] + row * 512;
            float ls = 0.f;
            #pragma unroll
            for (int i = 0; i < 8; ++i) {
                short8 xs = *(const short8*)(rbase + ((((qt * 8 + i)) ^ (row & 7)) << 4));
                short8 ws = *(const short8*)((const unsigned char*)wLb + qt * 128 + i * 16);
                #pragma unroll
                for (int e = 0; e < 8; ++e)
                    ls += bf2f((unsigned short)xs[e]) * bf2f((unsigned short)ws[e]);
            }
            ls += __shfl_xor(ls, 1);
            ls += __shfl_xor(ls, 2);
            if (qt == 0)
                out[(size_t)b * M_ + m0 + T * TR + row] = ls + bias0;
        }

        // convert + write next tile into the other buffer
        if (T + 1 < NT) {
            #pragma unroll
            for (int j = 0; j < 16; ++j) {
                const int row = j * 4 + wv;
                unsigned lo = (unsigned)f2bf(st[j].x) | ((unsigned)f2bf(st[j].y) << 16);
                unsigned hi = (unsigned)f2bf(st[j].z) | ((unsigned)f2bf(st[j].w) << 16);
                unsigned* d = (unsigned*)(xL[cur ^ 1] + row * 512 + ((swq ^ (row & 7)) << 4) + shf);
                d[0] = lo; d[1] = hi;
            }
        }
        __syncthreads();
    }

    // xv global write as bf16. C/D layout: col = l&15, row = (l>>4)*4 + reg.
    #pragma unroll
    for (int T = 0; T < NT; ++T) {
        const int rbase = m0 + T * TR + wv * 16 + (l >> 4) * 4;
        #pragma unroll
        for (int r = 0; r < 4; ++r)
            xvb[(size_t)(b * M_ + rbase + r) * K_ + (l & 15)] = f2bf(acc[T][r]);
    }

    // sv partial (fp32): sum all rows this lane holds, reduce 16/32, waves via LDS
    float s = 0.f;
    #pragma unroll
    for (int T = 0; T < NT; ++T)
        s += acc[T][0] + acc[T][1] + acc[T][2] + acc[T][3];
    s += __shfl_xor(s, 16);
    s += __shfl_xor(s, 32);
    if (l < 16) red[wv * 16 + l] = s;
    __syncthreads();
    if (t < 16)
        svpart[(size_t)blk * 16 + t] = red[t] + red[16 + t] + red[32 + t] + red[48 + t];
}

// ---------------- Pass 2 (bf16 xv read) ----------------
// grid = B_*2 blocks, 256 threads; thread per row (32B bf16 read).
__global__ __launch_bounds__(256) void fm_pass2(
    const unsigned short* __restrict__ xvb, const float* __restrict__ svpart,
    float* __restrict__ out)
{
    const int t = threadIdx.x;
    const int blk = blockIdx.x;
    const int b = blk >> 1;
    const int m = (blk & 1) * 256 + t;
    __shared__ __align__(16) float svL[16];
    if (t < 16)
        svL[t] = svpart[(size_t)(b * 2 + 0) * 16 + t] + svpart[(size_t)(b * 2 + 1) * 16 + t];
    __syncthreads();

    const unsigned short* xp = xvb + ((size_t)b * M_ + m) * K_;
    short8 h0 = *(const short8*)(xp);
    short8 h1 = *(const short8*)(xp + 8);

    float rs = 0.f, dg = 0.f;
    #pragma unroll
    for (int k = 0; k < 8; ++k) {
        const float a = bf2f((unsigned short)h0[k]);
        rs += a * svL[k];
        dg += a * a;
    }
    #pragma unroll
    for (int k = 0; k < 8; ++k) {
        const float a = bf2f((unsigned short)h1[k]);
        rs += a * svL[8 + k];
        dg += a * a;
    }

    const size_t o = (size_t)b * M_ + m;
    out[o] = out[o] + 0.5f * (rs - dg);
}

extern "C" void kernel_launch(void* const* d_in, const int* in_sizes, int n_in,
                              void* d_out, int out_size, void* d_ws, size_t ws_size,
                              hipStream_t stream) {
    const float* x    = (const float*)d_in[0];
    const float* w    = (const float*)d_in[1];
    const float* bias = (const float*)d_in[2];
    const float* v    = (const float*)d_in[3];
    float* out = (float*)d_out;

    unsigned short* xvb = (unsigned short*)d_ws;            // B*M*K bf16 = 4 MiB
    float* svpart = (float*)((char*)d_ws + ((size_t)B_ * M_ * K_ * 2));

    fm_pass1<<<dim3(B_ * 2), dim3(256), 0, stream>>>(x, w, bias, v, xvb, svpart, out);
    fm_pass2<<<dim3(B_ * 2), dim3(256), 0, stream>>>(xvb, svpart, out);
}